// Round 1
// baseline (457.809 us; speedup 1.0000x reference)
//
#include <hip/hip_runtime.h>
#include <hip/hip_bf16.h>
#include <cstdint>
#include <cstddef>

#define HID 16
#define IN  30
// chunk of 32 timesteps staged in LDS, padded to 32 floats per step

#if defined(__has_builtin)
#if __has_builtin(__builtin_amdgcn_rcpf)
#define FAST_RCP(x) __builtin_amdgcn_rcpf(x)
#endif
#endif
#ifndef FAST_RCP
#define FAST_RCP(x) (1.0f / (x))
#endif

__device__ __forceinline__ float fast_sigmoid(float x) {
    // 1/(1+exp(-x)); saturates correctly at +/-inf
    float e = __expf(-x);
    return FAST_RCP(1.0f + e);
}

__device__ __forceinline__ float fast_tanh(float x) {
    // 1 - 2/(exp(2x)+1); saturates correctly
    float e = __expf(2.0f * x);
    return fmaf(-2.0f, FAST_RCP(e + 1.0f), 1.0f);
}

__global__ __launch_bounds__(256) void gru_enc_kernel(
    const float* __restrict__ x, const int* __restrict__ lengths,
    const float* __restrict__ w_ih, const float* __restrict__ w_hh,
    const float* __restrict__ b_ih, const float* __restrict__ b_hh,
    const float* __restrict__ fc1w, const float* __restrict__ fc1b,
    const float* __restrict__ fc2w, const float* __restrict__ fc2b,
    const float* __restrict__ fc3w, const float* __restrict__ fc3b,
    float* __restrict__ out, int nrows, int T)
{
    // 4 waves/block, per wave: 2 chunks x 32 steps x 32 floats (padded from 30)
    __shared__ __align__(16) float lds[4 * 2 * 1024];

    const int tid  = threadIdx.x;
    const int w    = tid >> 6;
    const int lane = tid & 63;
    const int jj   = lane & 15;      // hidden index this lane owns
    const int g    = lane >> 4;      // 0=r, 1=z, 2=n, 3=spare (duplicates g=2)
    const int gw   = (g < 3) ? g : 2;
    const int row  = blockIdx.x * 4 + w;
    if (row >= nrows) return;        // wave-level exit; no __syncthreads in kernel

    float* lbuf = lds + w * 2048;

    const int wr = gw * HID + jj;    // weight row for this lane's gate output

    float wih[IN];
#pragma unroll
    for (int k = 0; k < IN; ++k) wih[k] = w_ih[wr * IN + k];
    float whh[HID];
#pragma unroll
    for (int k = 0; k < HID; ++k) whh[k] = w_hh[wr * HID + k];
    const float bi = b_ih[wr];
    const float bh = b_hh[wr];

    const int len  = lengths[row];
    const int nch  = (len + 31) >> 5;
    const float* xrow = x + (size_t)row * ((size_t)T * IN);

    float st[15];  // staging registers: 15*64 lanes = 960 floats = 32 steps * 30

    auto LOADC = [&](int c) {
        const float* gp = xrow + (size_t)c * 960 + lane;
#pragma unroll
        for (int i = 0; i < 15; ++i) st[i] = gp[i * 64];
    };
    auto WRITEC = [&](int c) {
        float* b = lbuf + (c & 1) * 1024;
#pragma unroll
        for (int i = 0; i < 15; ++i) {
            unsigned idx = (unsigned)(i * 64 + lane);
            unsigned s = idx / 30u;
            unsigned r = idx - s * 30u;
            b[s * 32 + r] = st[i];
        }
    };

    float h[HID];
#pragma unroll
    for (int k = 0; k < HID; ++k) h[k] = 0.0f;
    float h_own = 0.0f;

    // prologue: stage chunk 0, prefetch chunk 1
    LOADC(0);
    WRITEC(0);
    if (nch > 1) LOADC(1);

    for (int c = 0; c < nch; ++c) {
        const float* xb = lbuf + (c & 1) * 1024;
        const int tend = min(32, len - (c << 5));
        for (int ts = 0; ts < tend; ++ts) {
            const float4* xv4 = (const float4*)(xb + ts * 32);
            // input-side dot: 30 MACs (this lane's gate row)
            float xs = bi;
#pragma unroll
            for (int q = 0; q < 7; ++q) {
                float4 v = xv4[q];
                xs = fmaf(wih[4*q+0], v.x, xs);
                xs = fmaf(wih[4*q+1], v.y, xs);
                xs = fmaf(wih[4*q+2], v.z, xs);
                xs = fmaf(wih[4*q+3], v.w, xs);
            }
            {
                float2 v = *(const float2*)(xb + ts * 32 + 28);
                xs = fmaf(wih[28], v.x, xs);
                xs = fmaf(wih[29], v.y, xs);
            }
            // hidden-side dot: 16 MACs
            float hs = bh;
#pragma unroll
            for (int k = 0; k < HID; ++k) hs = fmaf(whh[k], h[k], hs);

            float sv = fast_sigmoid(xs + hs);   // valid for r (g=0) and z (g=1) lanes

            // gather the three gate pieces for hidden index jj
            float rj  = __shfl(sv, jj,      64);
            float zj  = __shfl(sv, jj + 16, 64);
            float xnj = __shfl(xs, jj + 32, 64);
            float hnj = __shfl(hs, jj + 32, 64);

            float n    = fast_tanh(fmaf(rj, hnj, xnj));
            float hnew = fmaf(zj, h_own - n, n);   // (1-z)*n + z*h
            h_own = hnew;

            // re-replicate full h vector into every lane
#pragma unroll
            for (int k = 0; k < HID; ++k) h[k] = __shfl(hnew, k, 64);
        }
        if (c + 1 < nch) {
            WRITEC(c + 1);               // compiler inserts vmcnt wait for LOADC(c+1)
            if (c + 2 < nch) LOADC(c + 2);
        }
    }

    // ---- FC head: e = relu-chain over 16x16 layers (computed redundantly per lane) ----
    float e1 = fc1b[jj];
#pragma unroll
    for (int k = 0; k < HID; ++k) e1 = fmaf(fc1w[jj * HID + k], h[k], e1);

    float v1[HID];
#pragma unroll
    for (int k = 0; k < HID; ++k) v1[k] = fmaxf(__shfl(e1, k, 64), 0.0f);

    float e2 = fc2b[jj];
#pragma unroll
    for (int k = 0; k < HID; ++k) e2 = fmaf(fc2w[jj * HID + k], v1[k], e2);

    float v2[HID];
#pragma unroll
    for (int k = 0; k < HID; ++k) v2[k] = fmaxf(__shfl(e2, k, 64), 0.0f);

    float e3 = fc3b[jj];
#pragma unroll
    for (int k = 0; k < HID; ++k) e3 = fmaf(fc3w[jj * HID + k], v2[k], e3);

    if (lane < HID) out[(size_t)row * HID + jj] = e3;
}

extern "C" void kernel_launch(void* const* d_in, const int* in_sizes, int n_in,
                              void* d_out, int out_size, void* d_ws, size_t ws_size,
                              hipStream_t stream) {
    const float* x     = (const float*)d_in[0];
    const int*   lens  = (const int*)d_in[1];
    const float* w_ih  = (const float*)d_in[2];
    const float* w_hh  = (const float*)d_in[3];
    const float* b_ih  = (const float*)d_in[4];
    const float* b_hh  = (const float*)d_in[5];
    const float* fc1w  = (const float*)d_in[6];
    const float* fc1b  = (const float*)d_in[7];
    const float* fc2w  = (const float*)d_in[8];
    const float* fc2b  = (const float*)d_in[9];
    const float* fc3w  = (const float*)d_in[10];
    const float* fc3b  = (const float*)d_in[11];
    float* out = (float*)d_out;

    const int B = in_sizes[1];
    const int T = (int)(in_sizes[0] / ((size_t)B * IN));
    const int grid = (B + 3) / 4;   // 4 rows (waves) per 256-thread block

    gru_enc_kernel<<<grid, 256, 0, stream>>>(x, lens, w_ih, w_hh, b_ih, b_hh,
                                             fc1w, fc1b, fc2w, fc2b, fc3w, fc3b,
                                             out, B, T);
}

// Round 2
// 210.547 us; speedup vs baseline: 2.1744x; 2.1744x over previous
//
#include <hip/hip_runtime.h>
#include <cstdint>
#include <cstddef>

typedef float v2f __attribute__((ext_vector_type(2)));

#define HID 16
#define IN  30

#define FAST_RCP(x) __builtin_amdgcn_rcpf(x)

__device__ __forceinline__ float fsig(float x) {
    float e = __expf(-x);
    return FAST_RCP(1.0f + e);
}
__device__ __forceinline__ float ftanh(float x) {
    float e = __expf(2.0f * x);
    return fmaf(-2.0f, FAST_RCP(e + 1.0f), 1.0f);
}
__device__ __forceinline__ float bperm(int baddr, float v) {
    return __int_as_float(__builtin_amdgcn_ds_bpermute(baddr, __float_as_int(v)));
}
__device__ __forceinline__ float xor16(float v) {
    // ds_swizzle BitMode: xor=0x10, and=0x1f -> lane ^ 16 (stays within 32-lane half)
    return __int_as_float(__builtin_amdgcn_ds_swizzle(__float_as_int(v), 0x401F));
}

// packed fp32 FMA: acc.xy += a.xy * b.xy
#define PKFMA(acc, a, b) asm("v_pk_fma_f32 %0, %1, %2, %0" : "+v"(acc) : "v"(a), "v"(b))

__global__ __launch_bounds__(256, 2) void gru_enc_kernel(
    const float* __restrict__ x, const int* __restrict__ lengths,
    const float* __restrict__ w_ih, const float* __restrict__ w_hh,
    const float* __restrict__ b_ih, const float* __restrict__ b_hh,
    const float* __restrict__ fc1w, const float* __restrict__ fc1b,
    const float* __restrict__ fc2w, const float* __restrict__ fc2b,
    const float* __restrict__ fc3w, const float* __restrict__ fc3b,
    float* __restrict__ out, int B, int T)
{
    const int lane = threadIdx.x & 63;
    const int wib  = threadIdx.x >> 6;
    const int gw   = blockIdx.x * 4 + wib;     // global wave id
    const int rbit = lane >> 5;                // which of the wave's 2 rows
    const int half = (lane >> 4) & 1;          // k-dimension half
    const int j    = lane & 15;                // hidden index owned by this lane

    int row = gw * 2 + rbit;
    const bool valid = (row < B);
    if (row >= B) row = B - 1;

    const int len = lengths[row];
    const int maxlen = max(len, __shfl_xor(len, 32));  // wave-uniform loop bound

    // ---- per-lane weights ----
    // input weights: half0 covers k=0..14 (16-float window k=0..15, pos15 zeroed),
    //                half1 covers k=15..29 (window k=14..29, pos0 zeroed)
    v2f wih2[3][8];
#pragma unroll
    for (int g = 0; g < 3; ++g) {
        const float* wr = w_ih + (size_t)(g * HID + j) * IN;
#pragma unroll
        for (int m = 0; m < 8; ++m) {
            int p0 = 2 * m, p1 = 2 * m + 1;
            float a, b;
            if (half) {
                a = (p0 == 0) ? 0.0f : wr[14 + p0];
                b = wr[14 + p1];
            } else {
                a = wr[p0];
                b = (p1 == 15) ? 0.0f : wr[p1];
            }
            v2f t; t.x = a; t.y = b;
            wih2[g][m] = t;
        }
    }
    float whh_l[3][8];
#pragma unroll
    for (int g = 0; g < 3; ++g)
#pragma unroll
        for (int m = 0; m < 8; ++m)
            whh_l[g][m] = w_hh[(size_t)(g * HID + j) * HID + half * 8 + m];

    const float bR  = b_ih[j]          + b_hh[j];
    const float bZ  = b_ih[HID + j]    + b_hh[HID + j];
    const float biN = b_ih[2*HID + j];
    const float bhN = b_hh[2*HID + j];

    // x base for this lane: its row, its half-window (8B aligned: 56B for half1)
    const float* xr = x + (size_t)row * T * IN + (half ? 14 : 0);

    // loop-invariant bpermute byte-addresses for h broadcast:
    // lane needs h_k for k = half*8 + m, canonical source = half0 lane of same row
    int baddr[8];
    {
        int bsrc = (lane & 32) | (half << 3);
#pragma unroll
        for (int m = 0; m < 8; ++m) baddr[m] = (bsrc + m) << 2;
    }

#define LOADX(buf, tt) do {                                        \
        const v2f* p_ = (const v2f*)(xr + (size_t)(tt) * IN);      \
        _Pragma("unroll")                                          \
        for (int m_ = 0; m_ < 8; ++m_) buf[m_] = p_[m_];           \
    } while (0)

#define STEP(t, xv) do {                                                    \
        v2f ar; ar.x = 0.f; ar.y = 0.f; v2f az = ar, an = ar;               \
        float hr = 0.f, hz = 0.f, hn = 0.f;                                 \
        _Pragma("unroll")                                                   \
        for (int m_ = 0; m_ < 8; ++m_) {                                    \
            PKFMA(ar, wih2[0][m_], xv[m_]);                                 \
            PKFMA(az, wih2[1][m_], xv[m_]);                                 \
            PKFMA(an, wih2[2][m_], xv[m_]);                                 \
            hr = fmaf(whh_l[0][m_], hbc[m_], hr);                           \
            hz = fmaf(whh_l[1][m_], hbc[m_], hz);                           \
            hn = fmaf(whh_l[2][m_], hbc[m_], hn);                           \
        }                                                                   \
        float pr  = ar.x + ar.y + hr;                                       \
        float pz  = az.x + az.y + hz;                                       \
        float pxn = an.x + an.y;                                            \
        float phn = hn;                                                     \
        pr  += xor16(pr);  pz  += xor16(pz);                                \
        pxn += xor16(pxn); phn += xor16(phn);                               \
        float rg = fsig(pr + bR);                                           \
        float zg = fsig(pz + bZ);                                           \
        float ng = ftanh(pxn + biN + rg * (phn + bhN));                     \
        float hnew = fmaf(zg, h_own - ng, ng);                              \
        last  = ((t) == len - 1) ? hnew : last;                             \
        h_own = hnew;                                                       \
        _Pragma("unroll")                                                   \
        for (int m_ = 0; m_ < 8; ++m_) hbc[m_] = bperm(baddr[m_], hnew);    \
    } while (0)

    float hbc[8];
#pragma unroll
    for (int m = 0; m < 8; ++m) hbc[m] = 0.0f;
    float h_own = 0.0f, last = 0.0f;

    v2f xa[8], xb[8];
    LOADX(xa, 0);
    LOADX(xb, (T > 1) ? 1 : 0);

    for (int t = 0; t < maxlen; t += 2) {
        STEP(t, xa);
        LOADX(xa, min(t + 2, T - 1));
        STEP(t + 1, xb);
        LOADX(xb, min(t + 3, T - 1));
    }

    // ---- FC head (once per row; redundantly on both halves) ----
    const int rb = lane & 32;
    float hv[16];
#pragma unroll
    for (int k = 0; k < 16; ++k) hv[k] = __shfl(last, rb + k, 64);

    float e1 = fc1b[j];
#pragma unroll
    for (int k = 0; k < 16; ++k) e1 = fmaf(fc1w[j * HID + k], hv[k], e1);

    float v1[16];
#pragma unroll
    for (int k = 0; k < 16; ++k) v1[k] = fmaxf(__shfl(e1, rb + k, 64), 0.0f);

    float e2 = fc2b[j];
#pragma unroll
    for (int k = 0; k < 16; ++k) e2 = fmaf(fc2w[j * HID + k], v1[k], e2);

    float v2a[16];
#pragma unroll
    for (int k = 0; k < 16; ++k) v2a[k] = fmaxf(__shfl(e2, rb + k, 64), 0.0f);

    float e3 = fc3b[j];
#pragma unroll
    for (int k = 0; k < 16; ++k) e3 = fmaf(fc3w[j * HID + k], v2a[k], e3);

    if (valid && half == 0) out[(size_t)row * HID + j] = e3;
}

extern "C" void kernel_launch(void* const* d_in, const int* in_sizes, int n_in,
                              void* d_out, int out_size, void* d_ws, size_t ws_size,
                              hipStream_t stream) {
    const float* x    = (const float*)d_in[0];
    const int*   lens = (const int*)d_in[1];
    const float* w_ih = (const float*)d_in[2];
    const float* w_hh = (const float*)d_in[3];
    const float* b_ih = (const float*)d_in[4];
    const float* b_hh = (const float*)d_in[5];
    const float* fc1w = (const float*)d_in[6];
    const float* fc1b = (const float*)d_in[7];
    const float* fc2w = (const float*)d_in[8];
    const float* fc2b = (const float*)d_in[9];
    const float* fc3w = (const float*)d_in[10];
    const float* fc3b = (const float*)d_in[11];
    float* out = (float*)d_out;

    const int B = in_sizes[1];
    const int T = (int)(in_sizes[0] / ((size_t)B * IN));
    const int grid = (B + 7) / 8;   // 8 rows per 256-thread block (2 rows/wave)

    gru_enc_kernel<<<grid, 256, 0, stream>>>(x, lens, w_ih, w_hh, b_ih, b_hh,
                                             fc1w, fc1b, fc2w, fc2b, fc3w, fc3b,
                                             out, B, T);
}

// Round 3
// 156.584 us; speedup vs baseline: 2.9237x; 1.3446x over previous
//
#include <hip/hip_runtime.h>
#include <cstdint>
#include <cstddef>

typedef float v2f __attribute__((ext_vector_type(2)));

#define HID 16
#define IN  30

#define FAST_RCP(x) __builtin_amdgcn_rcpf(x)

__device__ __forceinline__ float fsig(float x) {
    float e = __expf(-x);
    return FAST_RCP(1.0f + e);
}
__device__ __forceinline__ float ftanh(float x) {
    float e = __expf(2.0f * x);
    return fmaf(-2.0f, FAST_RCP(e + 1.0f), 1.0f);
}
__device__ __forceinline__ float bperm(int baddr, float v) {
    return __int_as_float(__builtin_amdgcn_ds_bpermute(baddr, __float_as_int(v)));
}
// quad_perm [1,0,3,2]: lane ^ 1 exchange, pure VALU (no LDS round-trip)
__device__ __forceinline__ float dppswap1(float v) {
    return __int_as_float(__builtin_amdgcn_mov_dpp(__float_as_int(v), 0xB1, 0xF, 0xF, true));
}
#define PKFMA(acc, a, b) asm("v_pk_fma_f32 %0, %1, %2, %0" : "+v"(acc) : "v"(a), "v"(b))

// ---------------- counting-sort kernels (bins by length, descending) ----------------
__global__ void k_hist(const int* __restrict__ len, int* __restrict__ hist, int B, int T) {
    int i = blockIdx.x * 256 + threadIdx.x;
    if (i < B) atomicAdd(hist + (T - len[i]), 1);
}
__global__ __launch_bounds__(512) void k_scan(const int* __restrict__ hist, int* __restrict__ off) {
    __shared__ int s[512];
    int t = threadIdx.x;
    int v = hist[t];
    s[t] = v; __syncthreads();
    int acc = v;
    for (int o = 1; o < 512; o <<= 1) {
        int add = (t >= o) ? s[t - o] : 0;
        __syncthreads();
        acc += add; s[t] = acc;
        __syncthreads();
    }
    off[t] = acc - v;   // exclusive prefix
}
__global__ void k_scatter(const int* __restrict__ len, int* __restrict__ off,
                          int* __restrict__ perm, int B, int T) {
    int i = blockIdx.x * 256 + threadIdx.x;
    if (i < B) {
        int b = T - len[i];
        int p = atomicAdd(off + b, 1);
        perm[p] = i;
    }
}

// ---------------- main GRU kernel: 8 waves/block, 2 rows/wave ----------------
__global__ __launch_bounds__(512, 2) void gru_enc_kernel(
    const float* __restrict__ x, const int* __restrict__ lengths,
    const float* __restrict__ w_ih, const float* __restrict__ w_hh,
    const float* __restrict__ b_ih, const float* __restrict__ b_hh,
    const float* __restrict__ fc1w, const float* __restrict__ fc1b,
    const float* __restrict__ fc2w, const float* __restrict__ fc2b,
    const float* __restrict__ fc3w, const float* __restrict__ fc3b,
    float* __restrict__ out, const int* __restrict__ perm,
    int B, int T, int NP, int nblk)
{
    const int lane = threadIdx.x & 63;
    const int wib  = threadIdx.x >> 6;        // wave in block, 0..7
    const int rb   = lane & 32;               // row-group bit
    const int half = lane & 1;                // k-dimension half (DPP-adjacent!)
    const int j    = (lane >> 1) & 15;        // hidden index owned

    // complementary schedule: waves 0-3 take long pairs from the front,
    // waves 4-7 take short pairs from the back -> waves i,i+4 share a SIMD
    int pos;
    if (wib < 4) pos = 4 * blockIdx.x + wib;
    else         pos = NP - 1 - (4 * blockIdx.x + (wib - 4));
    if (pos < 0 || pos >= NP) return;
    if (wib >= 4 && pos < 4 * nblk) return;   // overlap guard for ragged NP

    int ridx = 2 * pos + (rb >> 5);
    if (ridx >= B) ridx = B - 1;
    const int row = perm ? perm[ridx] : ridx;

    const int len = lengths[row];
    const int maxlen = max(len, __shfl_xor(len, 32));

    // ---- per-lane weights ----
    // input: half0 covers k=0..14 (window 0..15, p15 zeroed);
    //        half1 covers k=15..29 (window 14..29, p0 zeroed)
    v2f wih2[3][8];
#pragma unroll
    for (int g = 0; g < 3; ++g) {
        const float* wr = w_ih + (size_t)(g * HID + j) * IN;
#pragma unroll
        for (int m = 0; m < 8; ++m) {
            int p0 = 2 * m, p1 = 2 * m + 1;
            v2f t;
            if (half) { t.x = (p0 == 0) ? 0.0f : wr[14 + p0]; t.y = wr[14 + p1]; }
            else      { t.x = wr[p0]; t.y = (p1 == 15) ? 0.0f : wr[p1]; }
            wih2[g][m] = t;
        }
    }
    v2f whh2[3][4];
#pragma unroll
    for (int g = 0; g < 3; ++g)
#pragma unroll
        for (int m = 0; m < 4; ++m) {
            const float* wr = w_hh + (size_t)(g * HID + j) * HID + half * 8 + 2 * m;
            v2f t; t.x = wr[0]; t.y = wr[1];
            whh2[g][m] = t;
        }

    // biases folded into half-0 accumulator inits (appear once after DPP reduce)
    v2f initR; initR.x = half ? 0.0f : (b_ih[j] + b_hh[j]);               initR.y = 0.0f;
    v2f initZ; initZ.x = half ? 0.0f : (b_ih[HID + j] + b_hh[HID + j]);   initZ.y = 0.0f;
    v2f initN; initN.x = half ? 0.0f : b_ih[2 * HID + j];                 initN.y = 0.0f;
    v2f initH; initH.x = half ? 0.0f : b_hh[2 * HID + j];                 initH.y = 0.0f;

    const float* xr = x + (size_t)row * T * IN + (half ? 14 : 0);

    // bpermute byte addresses for h broadcast: lane needs h_k, k = half*8 + m;
    // source lane = rb | (k<<1)  (the half-0 lane owning j=k; both halves hold it)
    int ba0[4], ba1[4];
#pragma unroll
    for (int m = 0; m < 4; ++m) {
        int k0 = half * 8 + 2 * m;
        ba0[m] = (rb | (k0 << 1)) << 2;
        ba1[m] = (rb | ((k0 + 1) << 1)) << 2;
    }

#define LOADX(buf, tt) do {                                        \
        const v2f* p_ = (const v2f*)(xr + (size_t)(tt) * IN);      \
        _Pragma("unroll")                                          \
        for (int m_ = 0; m_ < 8; ++m_) buf[m_] = p_[m_];           \
    } while (0)

#define STEP(t, xv) do {                                                    \
        v2f ar = initR, az = initZ, an = initN, hn = initH;                 \
        _Pragma("unroll")                                                   \
        for (int m_ = 0; m_ < 8; ++m_) {                                    \
            PKFMA(ar, wih2[0][m_], xv[m_]);                                 \
            PKFMA(az, wih2[1][m_], xv[m_]);                                 \
            PKFMA(an, wih2[2][m_], xv[m_]);                                 \
        }                                                                   \
        _Pragma("unroll")                                                   \
        for (int m_ = 0; m_ < 4; ++m_) {                                    \
            PKFMA(ar, whh2[0][m_], hb2[m_]);                                \
            PKFMA(az, whh2[1][m_], hb2[m_]);                                \
            PKFMA(hn, whh2[2][m_], hb2[m_]);                                \
        }                                                                   \
        float pr  = ar.x + ar.y;  pr  += dppswap1(pr);                      \
        float pz  = az.x + az.y;  pz  += dppswap1(pz);                      \
        float pxn = an.x + an.y;  pxn += dppswap1(pxn);                     \
        float phn = hn.x + hn.y;  phn += dppswap1(phn);                     \
        float rg = fsig(pr);                                                \
        float zg = fsig(pz);                                                \
        float ng = ftanh(fmaf(rg, phn, pxn));                               \
        float hnew = fmaf(zg, h_own - ng, ng);                              \
        last  = ((t) == len - 1) ? hnew : last;                             \
        h_own = hnew;                                                       \
        _Pragma("unroll")                                                   \
        for (int m_ = 0; m_ < 4; ++m_) {                                    \
            hb2[m_].x = bperm(ba0[m_], hnew);                               \
            hb2[m_].y = bperm(ba1[m_], hnew);                               \
        }                                                                   \
    } while (0)

    v2f hb2[4];
#pragma unroll
    for (int m = 0; m < 4; ++m) { hb2[m].x = 0.0f; hb2[m].y = 0.0f; }
    float h_own = 0.0f, last = 0.0f;

    v2f xa[8], xb[8];
    LOADX(xa, 0);
    LOADX(xb, (T > 1) ? 1 : 0);

    const int tcap = T - 1;
    for (int t = 0; t < maxlen; t += 2) {
        STEP(t, xa);
        LOADX(xa, min(t + 2, tcap));
        STEP(t + 1, xb);
        LOADX(xb, min(t + 3, tcap));
    }

    // ---- FC head (redundant across halves; cheap, once per row) ----
    float hv[16];
#pragma unroll
    for (int k = 0; k < 16; ++k) hv[k] = __shfl(last, rb + 2 * k, 64);

    float e1 = fc1b[j];
#pragma unroll
    for (int k = 0; k < 16; ++k) e1 = fmaf(fc1w[j * HID + k], hv[k], e1);

    float v1[16];
#pragma unroll
    for (int k = 0; k < 16; ++k) v1[k] = fmaxf(__shfl(e1, rb + 2 * k, 64), 0.0f);

    float e2 = fc2b[j];
#pragma unroll
    for (int k = 0; k < 16; ++k) e2 = fmaf(fc2w[j * HID + k], v1[k], e2);

    float v2a[16];
#pragma unroll
    for (int k = 0; k < 16; ++k) v2a[k] = fmaxf(__shfl(e2, rb + 2 * k, 64), 0.0f);

    float e3 = fc3b[j];
#pragma unroll
    for (int k = 0; k < 16; ++k) e3 = fmaf(fc3w[j * HID + k], v2a[k], e3);

    if (half == 0) out[(size_t)row * HID + j] = e3;
}

extern "C" void kernel_launch(void* const* d_in, const int* in_sizes, int n_in,
                              void* d_out, int out_size, void* d_ws, size_t ws_size,
                              hipStream_t stream) {
    const float* x    = (const float*)d_in[0];
    const int*   lens = (const int*)d_in[1];
    const float* w_ih = (const float*)d_in[2];
    const float* w_hh = (const float*)d_in[3];
    const float* b_ih = (const float*)d_in[4];
    const float* b_hh = (const float*)d_in[5];
    const float* fc1w = (const float*)d_in[6];
    const float* fc1b = (const float*)d_in[7];
    const float* fc2w = (const float*)d_in[8];
    const float* fc2b = (const float*)d_in[9];
    const float* fc3w = (const float*)d_in[10];
    const float* fc3b = (const float*)d_in[11];
    float* out = (float*)d_out;

    const int B = in_sizes[1];
    const int T = (int)(in_sizes[0] / ((size_t)B * IN));

    // ws layout (ints): perm[B] | hist[512] | off[512]
    int* wsI = (int*)d_ws;
    const size_t need = ((size_t)B + 1024) * sizeof(int);
    const bool dosort = (ws_size >= need) && (T <= 512) && (T >= 1);
    int* perm = dosort ? wsI : nullptr;
    int* hist = wsI + B;
    int* off  = wsI + B + 512;

    if (dosort) {
        hipMemsetAsync(hist, 0, 512 * sizeof(int), stream);
        k_hist<<<(B + 255) / 256, 256, 0, stream>>>(lens, hist, B, T);
        k_scan<<<1, 512, 0, stream>>>(hist, off);
        k_scatter<<<(B + 255) / 256, 256, 0, stream>>>(lens, off, perm, B, T);
    }

    const int NP   = (B + 1) / 2;
    const int nblk = (NP + 7) / 8;
    gru_enc_kernel<<<nblk, 512, 0, stream>>>(x, lens, w_ih, w_hh, b_ih, b_hh,
                                             fc1w, fc1b, fc2w, fc2b, fc3w, fc3b,
                                             out, perm, B, T, NP, nblk);
}